// Round 15
// baseline (301.391 us; speedup 1.0000x reference)
//
#include <hip/hip_runtime.h>
#include <hip/hip_bf16.h>

#define BB 16384
#define TT 60
#define L2E 1.44269504089f

typedef short bf16x8 __attribute__((ext_vector_type(8)));
typedef float f32x4 __attribute__((ext_vector_type(4)));

__device__ __forceinline__ unsigned short f2bs(float f) {
    __hip_bfloat16 h = __float2bfloat16(f);
    return __builtin_bit_cast(unsigned short, h);
}

// single-op packed f32->2xbf16 (RNE)
__device__ __forceinline__ unsigned cvtpk2(float lo, float hi) {
    unsigned r;
    asm("v_cvt_pk_bf16_f32 %0, %1, %2" : "=v"(r) : "v"(lo), "v"(hi));
    return r;
}

// raw native 2^x (v_exp_f32); __builtin_exp2f lowers to the precise OCML path.
__device__ __forceinline__ float fexp2r(float x) {
    float r;
    asm("v_exp_f32 %0, %1" : "=v"(r) : "v"(x));
    return r;
}

// LSTM cell with exp2-folded gate pre-activations (yi,yf,yo = -log2e*x; yg = +2log2e*x).
__device__ __forceinline__ void lstm_cell(float yi, float yf, float yg, float yo,
                                          float& c, float& h) {
    yi = __builtin_amdgcn_fmed3f(yi, -24.53f, 24.53f);
    yf = __builtin_amdgcn_fmed3f(yf, -24.53f, 24.53f);
    yo = __builtin_amdgcn_fmed3f(yo, -24.53f, 24.53f);
    yg = __builtin_amdgcn_fmed3f(yg, -31.74f, 31.74f);
    const float ei = fexp2r(yi), ef = fexp2r(yf), eo = fexp2r(yo), eg = fexp2r(yg);
    const float di = 1.f + ei, df = 1.f + ef, dd = 1.f + eo, dg = 1.f + eg;
    const float a = di * df, b = dd * dg;
    const float R = __builtin_amdgcn_rcpf(a * b);
    const float si = df * b * R;
    const float sf = di * b * R;
    const float so = a * dg * R;
    const float tg = (eg - 1.f) * (a * dd) * R;
    const float cn = sf * c + si * tg;
    c = cn;
    const float tc = __builtin_amdgcn_fmed3f(cn, -11.f, 11.f);
    const float ec = fexp2r(tc * (2.f * L2E));
    const float th = (ec - 1.f) * __builtin_amdgcn_rcpf(ec + 1.f);
    h = so * th;
}

// Step barrier: LDS-only drain; global ops stay in flight.
#define STEP_BARRIER() do {                                   \
    asm volatile("s_waitcnt lgkmcnt(0)" ::: "memory");        \
    __builtin_amdgcn_s_barrier();                             \
    __builtin_amdgcn_sched_barrier(0);                        \
} while (0)

__device__ __forceinline__ bf16x8 pack8s(float4 a, float4 b, float s) {
    bf16x8 r;
    r[0] = (short)f2bs(a.x * s); r[1] = (short)f2bs(a.y * s);
    r[2] = (short)f2bs(a.z * s); r[3] = (short)f2bs(a.w * s);
    r[4] = (short)f2bs(b.x * s); r[5] = (short)f2bs(b.y * s);
    r[6] = (short)f2bs(b.z * s); r[7] = (short)f2bs(b.w * s);
    return r;
}

// ================= FUSED, M=16: LSTM1 (reverse) then LSTM2 (forward) + heads =================
// Block = 256 thr = 4 gate-split waves, ONE 16-batch tile. Grid 1024 -> 4 blocks/CU
// (vs M=32's grid-limited 2). launch_bounds(256,4) = 128-reg budget; M=16 body needs ~90-110.
__global__ __launch_bounds__(256, 4) void k_fused(
    const float* __restrict__ xmain, const float* __restrict__ aux,
    const float* __restrict__ Ws1, const float* __restrict__ bs1,
    const float* __restrict__ Ws2, const float* __restrict__ bs2,
    const float* __restrict__ Wih1, const float* __restrict__ Whh1,
    const float* __restrict__ bih1, const float* __restrict__ bhh1,
    const float* __restrict__ hx2, const float* __restrict__ cx2,
    const float* __restrict__ Wih2, const float* __restrict__ Whh2,
    const float* __restrict__ bih2, const float* __restrict__ bhh2,
    const float* __restrict__ Wlat, const float* __restrict__ blat,
    const float* __restrict__ Wout, const float* __restrict__ bout,
    const float* __restrict__ Wsfc, const float* __restrict__ bsfc,
    unsigned short* __restrict__ rnn1t, float* __restrict__ out)
{
    __shared__ unsigned short hB[2 * 2048];     // [buf][16][128] bf16, XOR-swizzled
    __shared__ unsigned short whead[16 * 64];   // head B-tile (phase B); rows 7..15 stay 0

    const int tid = threadIdx.x;
    {
        unsigned int* w32 = (unsigned int*)whead;
        w32[tid] = 0; w32[tid + 256] = 0;
    }
    const int hj = tid >> 6, lane = tid & 63;
    const int row16 = lane & 15, quad = lane >> 4;
    const int b0 = blockIdx.x * 16;
    const int swz = (row16 & 7) << 3;
    char* const hBb = (char*)hB;
    char* const whb = (char*)whead;

    // shared LDS byte offsets ([16][128] layout, both phases)
    const int j = hj * 16 + row16;
    const unsigned oA0 = (unsigned)(((row16 * 128 + 0 + quad * 8) ^ swz) * 2);
    const unsigned oA1 = (unsigned)(((row16 * 128 + 32 + quad * 8) ^ swz) * 2);
    const unsigned oA2 = (unsigned)(((row16 * 128 + 64 + quad * 8) ^ swz) * 2);
    const unsigned oA3 = (unsigned)(((row16 * 128 + 96 + quad * 8) ^ swz) * 2);
    unsigned oW[4];
    #pragma unroll
    for (int r = 0; r < 4; ++r) {
        const int m = quad * 4 + r;
        oW[r] = (unsigned)(((m * 128 + j) ^ ((m & 7) << 3)) * 2);
    }

    // ============================ PHASE A: LSTM1 ============================
    {
        {   // zero hB (cols 64..95 must be 0 for the a2 tail)
            unsigned int* p32 = (unsigned int*)hB;
            #pragma unroll
            for (int e = 0; e < 8; ++e) p32[tid + 256 * e] = 0;
        }
        // B fragments from GLOBAL, exp2-folded per gate (i,f,o: -L2E; g: +2*L2E)
        bf16x8 wf[4][3];
        float fb[4];
        #pragma unroll
        for (int i = 0; i < 4; ++i) {
            const float s = (i == 2) ? (2.f * L2E) : (-L2E);
            const int g = (hj + 4 * i) * 16 + row16;
            const float* wr = Whh1 + g * 64 + quad * 8;
            wf[i][0] = pack8s(*(const float4*)wr, *(const float4*)(wr + 4), s);
            wf[i][1] = pack8s(*(const float4*)(wr + 32), *(const float4*)(wr + 36), s);
            float4 z4 = {0.f, 0.f, 0.f, 0.f};
            float4 xw = z4;
            if (quad == 0) xw = *(const float4*)(Wih1 + g * 4);
            wf[i][2] = pack8s(xw, z4, s);
            fb[i] = (bih1[g] + bhh1[g]) * s;
        }
        __syncthreads();   // zero-init visible

        const unsigned oX = (unsigned)(((lane * 128 + 64) ^ ((lane & 7) << 3)) * 2);

        // init h0/c0 -> buf0 (surface MLP, unfolded)
        const float w10 = Ws1[j * 3], w11 = Ws1[j * 3 + 1], w12 = Ws1[j * 3 + 2], sb1v = bs1[j];
        const float w20 = Ws2[j * 3], w21 = Ws2[j * 3 + 1], w22 = Ws2[j * 3 + 2], sb2v = bs2[j];
        f32x4 cc;
        #pragma unroll
        for (int r = 0; r < 4; ++r) {
            const int m = quad * 4 + r;
            const float a0v = aux[(b0 + m) * 3], a1v = aux[(b0 + m) * 3 + 1], a2v = aux[(b0 + m) * 3 + 2];
            float h0 = w10 * a0v + w11 * a1v + w12 * a2v + sb1v;
            float c0in = w20 * a0v + w21 * a1v + w22 * a2v + sb2v;
            c0in = __builtin_amdgcn_fmed3f(c0in, -11.f, 11.f);
            const float e0 = fexp2r(c0in * (2.f * L2E));
            cc[r] = (e0 - 1.f) * __builtin_amdgcn_rcpf(e0 + 1.f);
            *(unsigned short*)(hBb + oW[r]) = f2bs(h0);
        }
        if (hj == 2 && lane < 16) {   // stage x_59 into buf0
            float4 xv = ((const float4*)xmain)[(size_t)(b0 + lane) * TT + 59];
            uint2 p2 = { cvtpk2(xv.x, xv.y), cvtpk2(xv.z, xv.w) };
            *(uint2*)(hBb + oX) = p2;
        }
        __syncthreads();

        // running global pointers
        const float4* px = (const float4*)xmain + (size_t)(b0 + lane) * TT + 58;
        unsigned short* pst = rnn1t + ((size_t)60 * BB + b0 + row16) * 64 + ((hj == 1) ? 32 : 0) + quad * 8;

        unsigned pofs = 0;
        #pragma unroll 1
        for (int s = 0; s < TT; ++s) {
            char* hbP = hBb + pofs;
            char* hbN = hBb + (pofs ^ 4096);
            float4 xv;
            if (hj == 2 && lane < 16 && s < TT - 1) xv = *px;   // prefetch x_{t-1}
            bf16x8 a0 = *(const bf16x8*)(hbP + oA0);
            bf16x8 a1 = *(const bf16x8*)(hbP + oA1);
            bf16x8 a2 = *(const bf16x8*)(hbP + oA2);
            if (s > 0 && hj < 2) {   // store h_{t+1} straight from A frags
                *(bf16x8*)pst = (hj == 0) ? a0 : a1;
            }
            pst -= (size_t)BB * 64;
            px -= 1;

            f32x4 ac[4];
            #pragma unroll
            for (int i = 0; i < 4; ++i) { f32x4 v = {fb[i], fb[i], fb[i], fb[i]}; ac[i] = v; }
            #pragma unroll
            for (int i = 0; i < 4; ++i) {
                ac[i] = __builtin_amdgcn_mfma_f32_16x16x32_bf16(a0, wf[i][0], ac[i], 0, 0, 0);
                ac[i] = __builtin_amdgcn_mfma_f32_16x16x32_bf16(a1, wf[i][1], ac[i], 0, 0, 0);
                ac[i] = __builtin_amdgcn_mfma_f32_16x16x32_bf16(a2, wf[i][2], ac[i], 0, 0, 0);
            }
            float hr[4];
            #pragma unroll
            for (int r = 0; r < 4; ++r) {
                float cr = cc[r];
                lstm_cell(ac[0][r], ac[1][r], ac[2][r], ac[3][r], cr, hr[r]);
                cc[r] = cr;
            }
            const unsigned u01 = cvtpk2(hr[0], hr[1]);
            const unsigned u23 = cvtpk2(hr[2], hr[3]);
            *(unsigned short*)(hbN + oW[0]) = (unsigned short)u01;
            *(unsigned short*)(hbN + oW[1]) = (unsigned short)(u01 >> 16);
            *(unsigned short*)(hbN + oW[2]) = (unsigned short)u23;
            *(unsigned short*)(hbN + oW[3]) = (unsigned short)(u23 >> 16);
            if (hj == 2 && lane < 16 && s < TT - 1) {
                uint2 p2 = { cvtpk2(xv.x, xv.y), cvtpk2(xv.z, xv.w) };
                *(uint2*)(hbN + oX) = p2;
            }
            STEP_BARRIER();
            pofs ^= 4096;
        }
        // epilogue: store h (slot 0)
        if (hj < 2) {
            char* hbP = hBb + pofs;
            bf16x8 sv = (hj == 0) ? *(const bf16x8*)(hbP + oA0)
                                  : *(const bf16x8*)(hbP + oA1);
            *(bf16x8*)&rnn1t[((size_t)(b0 + row16)) * 64 + ((hj == 1) ? 32 : 0) + quad * 8] = sv;
        }
    }

    // ---- transition: vmcnt(0)-draining barrier -> own rnn1t writes readable ----
    __syncthreads();

    // ============================ PHASE B: LSTM2 + heads ============================
    {
        // B fragments from GLOBAL, exp2-folded
        bf16x8 wf[4][4];
        float fb[4];
        #pragma unroll
        for (int i = 0; i < 4; ++i) {
            const float s = (i == 2) ? (2.f * L2E) : (-L2E);
            const int g = (hj + 4 * i) * 16 + row16;
            const float* wh = Whh2 + g * 64 + quad * 8;
            const float* wi = Wih2 + g * 64 + quad * 8;
            wf[i][0] = pack8s(*(const float4*)wh, *(const float4*)(wh + 4), s);
            wf[i][1] = pack8s(*(const float4*)(wh + 32), *(const float4*)(wh + 36), s);
            wf[i][2] = pack8s(*(const float4*)wi, *(const float4*)(wi + 4), s);
            wf[i][3] = pack8s(*(const float4*)(wi + 32), *(const float4*)(wi + 36), s);
            fb[i] = (bih2[g] + bhh2[g]) * s;
        }
        float bcomb = 0.f;
        if (row16 < 4) {
            float ss = 0.f;
            for (int jj = 0; jj < 64; ++jj) ss += Wout[row16 * 64 + jj] * blat[jj];
            bcomb = ss + bout[row16];
        } else if (row16 < 7) {
            bcomb = bsfc[row16 - 4];
        }
        {   // fill whead: rows 0..3 = Wout@Wlat, rows 4..6 = Wsfc (rows 7..15 remain 0)
            const int o = tid >> 6, k = tid & 63;
            float ss = 0.f;
            for (int jj = 0; jj < 64; ++jj) ss += Wout[o * 64 + jj] * Wlat[jj * 64 + k];
            whead[(o * 64 + k) ^ ((o & 7) << 3)] = f2bs(ss);
            if (tid < 192) {
                const int o2 = o + 4;
                whead[(o2 * 64 + k) ^ ((o2 & 7) << 3)] = f2bs(Wsfc[o * 64 + k]);
            }
        }

        const unsigned oPV = (hj == 0) ? oA2 : oA3;   // pv lands at cols 64.. / 96..
        const unsigned oH0 = (unsigned)(((row16 * 64 + 0 + quad * 8) ^ swz) * 2);
        const unsigned oH1 = (unsigned)(((row16 * 64 + 32 + quad * 8) ^ swz) * 2);

        // init h2_0/c2_0 -> buf0
        f32x4 cc;
        #pragma unroll
        for (int r = 0; r < 4; ++r) {
            const int m = quad * 4 + r;
            cc[r] = cx2[(size_t)(b0 + m) * 64 + j];
            *(unsigned short*)(hBb + oW[r]) = f2bs(hx2[(size_t)(b0 + m) * 64 + j]);
        }
        // stage h1_0 -> buf0 cols 64..127
        if (hj < 2) {
            bf16x8 v = *(const bf16x8*)&rnn1t[((size_t)(b0 + row16)) * 64 + ((hj == 1) ? 32 : 0) + quad * 8];
            *(bf16x8*)(hBb + oPV) = v;
        }
        __syncthreads();

        // head fragments (used by hj3)
        bf16x8 wh0 = *(const bf16x8*)(whb + oH0);
        bf16x8 wh1 = *(const bf16x8*)(whb + oH1);

        // running global pointers
        const unsigned short* ppv = rnn1t + ((size_t)BB + b0 + row16) * 64 + ((hj == 1) ? 32 : 0) + quad * 8;
        float* po = out + ((size_t)(b0 + quad * 4) * TT) * 4 + row16;

        unsigned pofs = 0;
        #pragma unroll 1
        for (int t = 0; t < TT; ++t) {
            char* hbP = hBb + pofs;
            char* hbN = hBb + (pofs ^ 4096);
            bf16x8 pv;
            if (hj < 2 && t < TT - 1) pv = *(const bf16x8*)ppv;   // prefetch h1_{t+1}
            ppv += (size_t)BB * 64;

            bf16x8 a0 = *(const bf16x8*)(hbP + oA0);
            bf16x8 a1 = *(const bf16x8*)(hbP + oA1);
            bf16x8 a2 = *(const bf16x8*)(hbP + oA2);
            bf16x8 a3 = *(const bf16x8*)(hbP + oA3);

            if (hj == 3 && t > 0) {   // head(h2_t, pre-update) -> out slot t-1
                f32x4 hacc = {bcomb, bcomb, bcomb, bcomb};
                hacc = __builtin_amdgcn_mfma_f32_16x16x32_bf16(a0, wh0, hacc, 0, 0, 0);
                hacc = __builtin_amdgcn_mfma_f32_16x16x32_bf16(a1, wh1, hacc, 0, 0, 0);
                if (row16 < 4) {
                    #pragma unroll
                    for (int r = 0; r < 4; ++r)
                        po[r * TT * 4] = hacc[r];
                }
                po += 4;
            }

            f32x4 ac[4];
            #pragma unroll
            for (int i = 0; i < 4; ++i) { f32x4 v = {fb[i], fb[i], fb[i], fb[i]}; ac[i] = v; }
            #pragma unroll
            for (int i = 0; i < 4; ++i) {
                ac[i] = __builtin_amdgcn_mfma_f32_16x16x32_bf16(a0, wf[i][0], ac[i], 0, 0, 0);
                ac[i] = __builtin_amdgcn_mfma_f32_16x16x32_bf16(a1, wf[i][1], ac[i], 0, 0, 0);
                ac[i] = __builtin_amdgcn_mfma_f32_16x16x32_bf16(a2, wf[i][2], ac[i], 0, 0, 0);
                ac[i] = __builtin_amdgcn_mfma_f32_16x16x32_bf16(a3, wf[i][3], ac[i], 0, 0, 0);
            }
            float hr[4];
            #pragma unroll
            for (int r = 0; r < 4; ++r) {
                float cr = cc[r];
                lstm_cell(ac[0][r], ac[1][r], ac[2][r], ac[3][r], cr, hr[r]);
                cc[r] = cr;
            }
            const unsigned u01 = cvtpk2(hr[0], hr[1]);
            const unsigned u23 = cvtpk2(hr[2], hr[3]);
            *(unsigned short*)(hbN + oW[0]) = (unsigned short)u01;
            *(unsigned short*)(hbN + oW[1]) = (unsigned short)(u01 >> 16);
            *(unsigned short*)(hbN + oW[2]) = (unsigned short)u23;
            *(unsigned short*)(hbN + oW[3]) = (unsigned short)(u23 >> 16);
            if (hj < 2 && t < TT - 1) *(bf16x8*)(hbN + oPV) = pv;
            STEP_BARRIER();
            pofs ^= 4096;
        }
        // epilogue: head(h2_60) -> slot 59 (cols 0..3) + relu sfc (cols 4..6)
        if (hj == 3) {
            char* hbP = hBb + pofs;
            bf16x8 ea0 = *(const bf16x8*)(hbP + oA0);
            bf16x8 ea1 = *(const bf16x8*)(hbP + oA1);
            f32x4 hacc = {bcomb, bcomb, bcomb, bcomb};
            hacc = __builtin_amdgcn_mfma_f32_16x16x32_bf16(ea0, wh0, hacc, 0, 0, 0);
            hacc = __builtin_amdgcn_mfma_f32_16x16x32_bf16(ea1, wh1, hacc, 0, 0, 0);
            if (row16 < 4) {
                #pragma unroll
                for (int r = 0; r < 4; ++r)
                    out[((size_t)(b0 + quad * 4 + r) * TT + 59) * 4 + row16] = hacc[r];
            } else if (row16 < 7) {
                float* osfc = out + (size_t)BB * TT * 4;
                #pragma unroll
                for (int r = 0; r < 4; ++r)
                    osfc[(size_t)(b0 + quad * 4 + r) * 3 + (row16 - 4)] = fmaxf(hacc[r], 0.f);
            }
        }
    }
}

extern "C" void kernel_launch(void* const* d_in, const int* in_sizes, int n_in,
                              void* d_out, int out_size, void* d_ws, size_t ws_size,
                              hipStream_t stream) {
    const float* xmain = (const float*)d_in[0];
    const float* aux   = (const float*)d_in[1];
    const float* hx2   = (const float*)d_in[2];
    const float* cx2   = (const float*)d_in[3];
    const float* Ws1   = (const float*)d_in[4];
    const float* bs1   = (const float*)d_in[5];
    const float* Ws2   = (const float*)d_in[6];
    const float* bs2   = (const float*)d_in[7];
    const float* Wih1  = (const float*)d_in[8];
    const float* Whh1  = (const float*)d_in[9];
    const float* bih1  = (const float*)d_in[10];
    const float* bhh1  = (const float*)d_in[11];
    const float* Wih2  = (const float*)d_in[12];
    const float* Whh2  = (const float*)d_in[13];
    const float* bih2  = (const float*)d_in[14];
    const float* bhh2  = (const float*)d_in[15];
    const float* Wlat  = (const float*)d_in[16];
    const float* blat  = (const float*)d_in[17];
    const float* Wout  = (const float*)d_in[18];
    const float* bout  = (const float*)d_in[19];
    const float* Wsfc  = (const float*)d_in[20];
    const float* bsfc  = (const float*)d_in[21];

    unsigned short* rnn1t = (unsigned short*)d_ws;   // [T][B][64] bf16 (private per-block slices)
    float* out = (float*)d_out;

    dim3 grid(BB / 16), block(256);
    k_fused<<<grid, block, 0, stream>>>(xmain, aux, Ws1, bs1, Ws2, bs2,
                                        Wih1, Whh1, bih1, bhh1,
                                        hx2, cx2, Wih2, Whh2, bih2, bhh2,
                                        Wlat, blat, Wout, bout, Wsfc, bsfc,
                                        rnn1t, out);
}

// Round 16
// 242.550 us; speedup vs baseline: 1.2426x; 1.2426x over previous
//
#include <hip/hip_runtime.h>
#include <hip/hip_bf16.h>

#define BB 16384
#define TT 60
#define L2E 1.44269504089f

typedef short bf16x8 __attribute__((ext_vector_type(8)));
typedef float f32x4 __attribute__((ext_vector_type(4)));

__device__ __forceinline__ unsigned short f2bs(float f) {
    __hip_bfloat16 h = __float2bfloat16(f);
    return __builtin_bit_cast(unsigned short, h);
}

// single-op packed f32->2xbf16 (RNE)
__device__ __forceinline__ unsigned cvtpk2(float lo, float hi) {
    unsigned r;
    asm("v_cvt_pk_bf16_f32 %0, %1, %2" : "=v"(r) : "v"(lo), "v"(hi));
    return r;
}

// raw native 2^x (v_exp_f32); __builtin_exp2f lowers to the precise OCML path.
__device__ __forceinline__ float fexp2r(float x) {
    float r;
    asm("v_exp_f32 %0, %1" : "=v"(r) : "v"(x));
    return r;
}

// LSTM cell with exp2-folded gate pre-activations (yi,yf,yo = -log2e*x; yg = +2log2e*x).
__device__ __forceinline__ void lstm_cell(float yi, float yf, float yg, float yo,
                                          float& c, float& h) {
    yi = __builtin_amdgcn_fmed3f(yi, -24.53f, 24.53f);
    yf = __builtin_amdgcn_fmed3f(yf, -24.53f, 24.53f);
    yo = __builtin_amdgcn_fmed3f(yo, -24.53f, 24.53f);
    yg = __builtin_amdgcn_fmed3f(yg, -31.74f, 31.74f);
    const float ei = fexp2r(yi), ef = fexp2r(yf), eo = fexp2r(yo), eg = fexp2r(yg);
    const float di = 1.f + ei, df = 1.f + ef, dd = 1.f + eo, dg = 1.f + eg;
    const float a = di * df, b = dd * dg;
    const float R = __builtin_amdgcn_rcpf(a * b);
    const float si = df * b * R;
    const float sf = di * b * R;
    const float so = a * dg * R;
    const float tg = (eg - 1.f) * (a * dd) * R;
    const float cn = sf * c + si * tg;
    c = cn;
    const float tc = __builtin_amdgcn_fmed3f(cn, -11.f, 11.f);
    const float ec = fexp2r(tc * (2.f * L2E));
    const float th = (ec - 1.f) * __builtin_amdgcn_rcpf(ec + 1.f);
    h = so * th;
}

// Step barrier: LDS-only drain; global ops stay in flight.
#define STEP_BARRIER() do {                                   \
    asm volatile("s_waitcnt lgkmcnt(0)" ::: "memory");        \
    __builtin_amdgcn_s_barrier();                             \
    __builtin_amdgcn_sched_barrier(0);                        \
} while (0)

__device__ __forceinline__ bf16x8 pack8s(float4 a, float4 b, float s) {
    bf16x8 r;
    r[0] = (short)f2bs(a.x * s); r[1] = (short)f2bs(a.y * s);
    r[2] = (short)f2bs(a.z * s); r[3] = (short)f2bs(a.w * s);
    r[4] = (short)f2bs(b.x * s); r[5] = (short)f2bs(b.y * s);
    r[6] = (short)f2bs(b.z * s); r[7] = (short)f2bs(b.w * s);
    return r;
}

// ================= FUSED, M=16: LSTM1 (reverse) then LSTM2 (forward) + heads =================
// Block = 256 thr = 4 gate-split waves, ONE 16-batch tile. Grid 1024 -> 4 blocks/CU.
// launch_bounds(256,3) = 84-reg cap (R5/R13-verified mapping); M=16 body needs ~65-80
// (R14 M=32 unconstrained = 96, minus ~32 for halved acc/frags). (256,4)=64 spilled (R15).
__global__ __launch_bounds__(256, 3) void k_fused(
    const float* __restrict__ xmain, const float* __restrict__ aux,
    const float* __restrict__ Ws1, const float* __restrict__ bs1,
    const float* __restrict__ Ws2, const float* __restrict__ bs2,
    const float* __restrict__ Wih1, const float* __restrict__ Whh1,
    const float* __restrict__ bih1, const float* __restrict__ bhh1,
    const float* __restrict__ hx2, const float* __restrict__ cx2,
    const float* __restrict__ Wih2, const float* __restrict__ Whh2,
    const float* __restrict__ bih2, const float* __restrict__ bhh2,
    const float* __restrict__ Wlat, const float* __restrict__ blat,
    const float* __restrict__ Wout, const float* __restrict__ bout,
    const float* __restrict__ Wsfc, const float* __restrict__ bsfc,
    unsigned short* __restrict__ rnn1t, float* __restrict__ out)
{
    __shared__ unsigned short hB[2 * 2048];     // [buf][16][128] bf16, XOR-swizzled
    __shared__ unsigned short whead[16 * 64];   // head B-tile (phase B); rows 7..15 stay 0

    const int tid = threadIdx.x;
    {
        unsigned int* w32 = (unsigned int*)whead;
        w32[tid] = 0; w32[tid + 256] = 0;
    }
    const int hj = tid >> 6, lane = tid & 63;
    const int row16 = lane & 15, quad = lane >> 4;
    const int b0 = blockIdx.x * 16;
    const int swz = (row16 & 7) << 3;
    char* const hBb = (char*)hB;
    char* const whb = (char*)whead;

    // shared LDS byte offsets ([16][128] layout, both phases)
    const int j = hj * 16 + row16;
    const unsigned oA0 = (unsigned)(((row16 * 128 + 0 + quad * 8) ^ swz) * 2);
    const unsigned oA1 = (unsigned)(((row16 * 128 + 32 + quad * 8) ^ swz) * 2);
    const unsigned oA2 = (unsigned)(((row16 * 128 + 64 + quad * 8) ^ swz) * 2);
    const unsigned oA3 = (unsigned)(((row16 * 128 + 96 + quad * 8) ^ swz) * 2);
    unsigned oW[4];
    #pragma unroll
    for (int r = 0; r < 4; ++r) {
        const int m = quad * 4 + r;
        oW[r] = (unsigned)(((m * 128 + j) ^ ((m & 7) << 3)) * 2);
    }

    // ============================ PHASE A: LSTM1 ============================
    {
        {   // zero hB (cols 64..95 must be 0 for the a2 tail)
            unsigned int* p32 = (unsigned int*)hB;
            #pragma unroll
            for (int e = 0; e < 8; ++e) p32[tid + 256 * e] = 0;
        }
        // B fragments from GLOBAL, exp2-folded per gate (i,f,o: -L2E; g: +2*L2E)
        bf16x8 wf[4][3];
        float fb[4];
        #pragma unroll
        for (int i = 0; i < 4; ++i) {
            const float s = (i == 2) ? (2.f * L2E) : (-L2E);
            const int g = (hj + 4 * i) * 16 + row16;
            const float* wr = Whh1 + g * 64 + quad * 8;
            wf[i][0] = pack8s(*(const float4*)wr, *(const float4*)(wr + 4), s);
            wf[i][1] = pack8s(*(const float4*)(wr + 32), *(const float4*)(wr + 36), s);
            float4 z4 = {0.f, 0.f, 0.f, 0.f};
            float4 xw = z4;
            if (quad == 0) xw = *(const float4*)(Wih1 + g * 4);
            wf[i][2] = pack8s(xw, z4, s);
            fb[i] = (bih1[g] + bhh1[g]) * s;
        }
        __syncthreads();   // zero-init visible

        const unsigned oX = (unsigned)(((lane * 128 + 64) ^ ((lane & 7) << 3)) * 2);

        // init h0/c0 -> buf0 (surface MLP, unfolded)
        const float w10 = Ws1[j * 3], w11 = Ws1[j * 3 + 1], w12 = Ws1[j * 3 + 2], sb1v = bs1[j];
        const float w20 = Ws2[j * 3], w21 = Ws2[j * 3 + 1], w22 = Ws2[j * 3 + 2], sb2v = bs2[j];
        f32x4 cc;
        #pragma unroll
        for (int r = 0; r < 4; ++r) {
            const int m = quad * 4 + r;
            const float a0v = aux[(b0 + m) * 3], a1v = aux[(b0 + m) * 3 + 1], a2v = aux[(b0 + m) * 3 + 2];
            float h0 = w10 * a0v + w11 * a1v + w12 * a2v + sb1v;
            float c0in = w20 * a0v + w21 * a1v + w22 * a2v + sb2v;
            c0in = __builtin_amdgcn_fmed3f(c0in, -11.f, 11.f);
            const float e0 = fexp2r(c0in * (2.f * L2E));
            cc[r] = (e0 - 1.f) * __builtin_amdgcn_rcpf(e0 + 1.f);
            *(unsigned short*)(hBb + oW[r]) = f2bs(h0);
        }
        if (hj == 2 && lane < 16) {   // stage x_59 into buf0
            float4 xv = ((const float4*)xmain)[(size_t)(b0 + lane) * TT + 59];
            uint2 p2 = { cvtpk2(xv.x, xv.y), cvtpk2(xv.z, xv.w) };
            *(uint2*)(hBb + oX) = p2;
        }
        __syncthreads();

        // running global pointers
        const float4* px = (const float4*)xmain + (size_t)(b0 + lane) * TT + 58;
        unsigned short* pst = rnn1t + ((size_t)60 * BB + b0 + row16) * 64 + ((hj == 1) ? 32 : 0) + quad * 8;

        unsigned pofs = 0;
        #pragma unroll 1
        for (int s = 0; s < TT; ++s) {
            char* hbP = hBb + pofs;
            char* hbN = hBb + (pofs ^ 4096);
            float4 xv;
            if (hj == 2 && lane < 16 && s < TT - 1) xv = *px;   // prefetch x_{t-1}
            bf16x8 a0 = *(const bf16x8*)(hbP + oA0);
            bf16x8 a1 = *(const bf16x8*)(hbP + oA1);
            bf16x8 a2 = *(const bf16x8*)(hbP + oA2);
            if (s > 0 && hj < 2) {   // store h_{t+1} straight from A frags
                *(bf16x8*)pst = (hj == 0) ? a0 : a1;
            }
            pst -= (size_t)BB * 64;
            px -= 1;

            f32x4 ac[4];
            #pragma unroll
            for (int i = 0; i < 4; ++i) { f32x4 v = {fb[i], fb[i], fb[i], fb[i]}; ac[i] = v; }
            #pragma unroll
            for (int i = 0; i < 4; ++i) {
                ac[i] = __builtin_amdgcn_mfma_f32_16x16x32_bf16(a0, wf[i][0], ac[i], 0, 0, 0);
                ac[i] = __builtin_amdgcn_mfma_f32_16x16x32_bf16(a1, wf[i][1], ac[i], 0, 0, 0);
                ac[i] = __builtin_amdgcn_mfma_f32_16x16x32_bf16(a2, wf[i][2], ac[i], 0, 0, 0);
            }
            float hr[4];
            #pragma unroll
            for (int r = 0; r < 4; ++r) {
                float cr = cc[r];
                lstm_cell(ac[0][r], ac[1][r], ac[2][r], ac[3][r], cr, hr[r]);
                cc[r] = cr;
            }
            const unsigned u01 = cvtpk2(hr[0], hr[1]);
            const unsigned u23 = cvtpk2(hr[2], hr[3]);
            *(unsigned short*)(hbN + oW[0]) = (unsigned short)u01;
            *(unsigned short*)(hbN + oW[1]) = (unsigned short)(u01 >> 16);
            *(unsigned short*)(hbN + oW[2]) = (unsigned short)u23;
            *(unsigned short*)(hbN + oW[3]) = (unsigned short)(u23 >> 16);
            if (hj == 2 && lane < 16 && s < TT - 1) {
                uint2 p2 = { cvtpk2(xv.x, xv.y), cvtpk2(xv.z, xv.w) };
                *(uint2*)(hbN + oX) = p2;
            }
            STEP_BARRIER();
            pofs ^= 4096;
        }
        // epilogue: store h (slot 0)
        if (hj < 2) {
            char* hbP = hBb + pofs;
            bf16x8 sv = (hj == 0) ? *(const bf16x8*)(hbP + oA0)
                                  : *(const bf16x8*)(hbP + oA1);
            *(bf16x8*)&rnn1t[((size_t)(b0 + row16)) * 64 + ((hj == 1) ? 32 : 0) + quad * 8] = sv;
        }
    }

    // ---- transition: vmcnt(0)-draining barrier -> own rnn1t writes readable ----
    __syncthreads();

    // ============================ PHASE B: LSTM2 + heads ============================
    {
        // B fragments from GLOBAL, exp2-folded
        bf16x8 wf[4][4];
        float fb[4];
        #pragma unroll
        for (int i = 0; i < 4; ++i) {
            const float s = (i == 2) ? (2.f * L2E) : (-L2E);
            const int g = (hj + 4 * i) * 16 + row16;
            const float* wh = Whh2 + g * 64 + quad * 8;
            const float* wi = Wih2 + g * 64 + quad * 8;
            wf[i][0] = pack8s(*(const float4*)wh, *(const float4*)(wh + 4), s);
            wf[i][1] = pack8s(*(const float4*)(wh + 32), *(const float4*)(wh + 36), s);
            wf[i][2] = pack8s(*(const float4*)wi, *(const float4*)(wi + 4), s);
            wf[i][3] = pack8s(*(const float4*)(wi + 32), *(const float4*)(wi + 36), s);
            fb[i] = (bih2[g] + bhh2[g]) * s;
        }
        float bcomb = 0.f;
        if (row16 < 4) {
            float ss = 0.f;
            for (int jj = 0; jj < 64; ++jj) ss += Wout[row16 * 64 + jj] * blat[jj];
            bcomb = ss + bout[row16];
        } else if (row16 < 7) {
            bcomb = bsfc[row16 - 4];
        }
        {   // fill whead: rows 0..3 = Wout@Wlat, rows 4..6 = Wsfc (rows 7..15 remain 0)
            const int o = tid >> 6, k = tid & 63;
            float ss = 0.f;
            for (int jj = 0; jj < 64; ++jj) ss += Wout[o * 64 + jj] * Wlat[jj * 64 + k];
            whead[(o * 64 + k) ^ ((o & 7) << 3)] = f2bs(ss);
            if (tid < 192) {
                const int o2 = o + 4;
                whead[(o2 * 64 + k) ^ ((o2 & 7) << 3)] = f2bs(Wsfc[o * 64 + k]);
            }
        }

        const unsigned oPV = (hj == 0) ? oA2 : oA3;   // pv lands at cols 64.. / 96..
        const unsigned oH0 = (unsigned)(((row16 * 64 + 0 + quad * 8) ^ swz) * 2);
        const unsigned oH1 = (unsigned)(((row16 * 64 + 32 + quad * 8) ^ swz) * 2);

        // init h2_0/c2_0 -> buf0
        f32x4 cc;
        #pragma unroll
        for (int r = 0; r < 4; ++r) {
            const int m = quad * 4 + r;
            cc[r] = cx2[(size_t)(b0 + m) * 64 + j];
            *(unsigned short*)(hBb + oW[r]) = f2bs(hx2[(size_t)(b0 + m) * 64 + j]);
        }
        // stage h1_0 -> buf0 cols 64..127
        if (hj < 2) {
            bf16x8 v = *(const bf16x8*)&rnn1t[((size_t)(b0 + row16)) * 64 + ((hj == 1) ? 32 : 0) + quad * 8];
            *(bf16x8*)(hBb + oPV) = v;
        }
        __syncthreads();

        // head fragments (used by hj3)
        bf16x8 wh0 = *(const bf16x8*)(whb + oH0);
        bf16x8 wh1 = *(const bf16x8*)(whb + oH1);

        // running global pointers
        const unsigned short* ppv = rnn1t + ((size_t)BB + b0 + row16) * 64 + ((hj == 1) ? 32 : 0) + quad * 8;
        float* po = out + ((size_t)(b0 + quad * 4) * TT) * 4 + row16;

        unsigned pofs = 0;
        #pragma unroll 1
        for (int t = 0; t < TT; ++t) {
            char* hbP = hBb + pofs;
            char* hbN = hBb + (pofs ^ 4096);
            bf16x8 pv;
            if (hj < 2 && t < TT - 1) pv = *(const bf16x8*)ppv;   // prefetch h1_{t+1}
            ppv += (size_t)BB * 64;

            bf16x8 a0 = *(const bf16x8*)(hbP + oA0);
            bf16x8 a1 = *(const bf16x8*)(hbP + oA1);
            bf16x8 a2 = *(const bf16x8*)(hbP + oA2);
            bf16x8 a3 = *(const bf16x8*)(hbP + oA3);

            if (hj == 3 && t > 0) {   // head(h2_t, pre-update) -> out slot t-1
                f32x4 hacc = {bcomb, bcomb, bcomb, bcomb};
                hacc = __builtin_amdgcn_mfma_f32_16x16x32_bf16(a0, wh0, hacc, 0, 0, 0);
                hacc = __builtin_amdgcn_mfma_f32_16x16x32_bf16(a1, wh1, hacc, 0, 0, 0);
                if (row16 < 4) {
                    #pragma unroll
                    for (int r = 0; r < 4; ++r)
                        po[r * TT * 4] = hacc[r];
                }
                po += 4;
            }

            f32x4 ac[4];
            #pragma unroll
            for (int i = 0; i < 4; ++i) { f32x4 v = {fb[i], fb[i], fb[i], fb[i]}; ac[i] = v; }
            #pragma unroll
            for (int i = 0; i < 4; ++i) {
                ac[i] = __builtin_amdgcn_mfma_f32_16x16x32_bf16(a0, wf[i][0], ac[i], 0, 0, 0);
                ac[i] = __builtin_amdgcn_mfma_f32_16x16x32_bf16(a1, wf[i][1], ac[i], 0, 0, 0);
                ac[i] = __builtin_amdgcn_mfma_f32_16x16x32_bf16(a2, wf[i][2], ac[i], 0, 0, 0);
                ac[i] = __builtin_amdgcn_mfma_f32_16x16x32_bf16(a3, wf[i][3], ac[i], 0, 0, 0);
            }
            float hr[4];
            #pragma unroll
            for (int r = 0; r < 4; ++r) {
                float cr = cc[r];
                lstm_cell(ac[0][r], ac[1][r], ac[2][r], ac[3][r], cr, hr[r]);
                cc[r] = cr;
            }
            const unsigned u01 = cvtpk2(hr[0], hr[1]);
            const unsigned u23 = cvtpk2(hr[2], hr[3]);
            *(unsigned short*)(hbN + oW[0]) = (unsigned short)u01;
            *(unsigned short*)(hbN + oW[1]) = (unsigned short)(u01 >> 16);
            *(unsigned short*)(hbN + oW[2]) = (unsigned short)u23;
            *(unsigned short*)(hbN + oW[3]) = (unsigned short)(u23 >> 16);
            if (hj < 2 && t < TT - 1) *(bf16x8*)(hbN + oPV) = pv;
            STEP_BARRIER();
            pofs ^= 4096;
        }
        // epilogue: head(h2_60) -> slot 59 (cols 0..3) + relu sfc (cols 4..6)
        if (hj == 3) {
            char* hbP = hBb + pofs;
            bf16x8 ea0 = *(const bf16x8*)(hbP + oA0);
            bf16x8 ea1 = *(const bf16x8*)(hbP + oA1);
            f32x4 hacc = {bcomb, bcomb, bcomb, bcomb};
            hacc = __builtin_amdgcn_mfma_f32_16x16x32_bf16(ea0, wh0, hacc, 0, 0, 0);
            hacc = __builtin_amdgcn_mfma_f32_16x16x32_bf16(ea1, wh1, hacc, 0, 0, 0);
            if (row16 < 4) {
                #pragma unroll
                for (int r = 0; r < 4; ++r)
                    out[((size_t)(b0 + quad * 4 + r) * TT + 59) * 4 + row16] = hacc[r];
            } else if (row16 < 7) {
                float* osfc = out + (size_t)BB * TT * 4;
                #pragma unroll
                for (int r = 0; r < 4; ++r)
                    osfc[(size_t)(b0 + quad * 4 + r) * 3 + (row16 - 4)] = fmaxf(hacc[r], 0.f);
            }
        }
    }
}

extern "C" void kernel_launch(void* const* d_in, const int* in_sizes, int n_in,
                              void* d_out, int out_size, void* d_ws, size_t ws_size,
                              hipStream_t stream) {
    const float* xmain = (const float*)d_in[0];
    const float* aux   = (const float*)d_in[1];
    const float* hx2   = (const float*)d_in[2];
    const float* cx2   = (const float*)d_in[3];
    const float* Ws1   = (const float*)d_in[4];
    const float* bs1   = (const float*)d_in[5];
    const float* Ws2   = (const float*)d_in[6];
    const float* bs2   = (const float*)d_in[7];
    const float* Wih1  = (const float*)d_in[8];
    const float* Whh1  = (const float*)d_in[9];
    const float* bih1  = (const float*)d_in[10];
    const float* bhh1  = (const float*)d_in[11];
    const float* Wih2  = (const float*)d_in[12];
    const float* Whh2  = (const float*)d_in[13];
    const float* bih2  = (const float*)d_in[14];
    const float* bhh2  = (const float*)d_in[15];
    const float* Wlat  = (const float*)d_in[16];
    const float* blat  = (const float*)d_in[17];
    const float* Wout  = (const float*)d_in[18];
    const float* bout  = (const float*)d_in[19];
    const float* Wsfc  = (const float*)d_in[20];
    const float* bsfc  = (const float*)d_in[21];

    unsigned short* rnn1t = (unsigned short*)d_ws;   // [T][B][64] bf16 (private per-block slices)
    float* out = (float*)d_out;

    dim3 grid(BB / 16), block(256);
    k_fused<<<grid, block, 0, stream>>>(xmain, aux, Ws1, bs1, Ws2, bs2,
                                        Wih1, Whh1, bih1, bhh1,
                                        hx2, cx2, Wih2, Whh2, bih2, bhh2,
                                        Wlat, blat, Wout, bout, Wsfc, bsfc,
                                        rnn1t, out);
}

// Round 17
// 227.811 us; speedup vs baseline: 1.3230x; 1.0647x over previous
//
#include <hip/hip_runtime.h>
#include <hip/hip_bf16.h>

#define BB 16384
#define TT 60
#define L2E 1.44269504089f

typedef short bf16x8 __attribute__((ext_vector_type(8)));
typedef float f32x4 __attribute__((ext_vector_type(4)));

__device__ __forceinline__ unsigned short f2bs(float f) {
    __hip_bfloat16 h = __float2bfloat16(f);
    return __builtin_bit_cast(unsigned short, h);
}

// single-op packed f32->2xbf16 (RNE)
__device__ __forceinline__ unsigned cvtpk2(float lo, float hi) {
    unsigned r;
    asm("v_cvt_pk_bf16_f32 %0, %1, %2" : "=v"(r) : "v"(lo), "v"(hi));
    return r;
}

// raw native 2^x (v_exp_f32); __builtin_exp2f lowers to the precise OCML path.
__device__ __forceinline__ float fexp2r(float x) {
    float r;
    asm("v_exp_f32 %0, %1" : "=v"(r) : "v"(x));
    return r;
}

// LSTM cell with exp2-folded gate pre-activations (yi,yf,yo = -log2e*x; yg = +2log2e*x).
__device__ __forceinline__ void lstm_cell(float yi, float yf, float yg, float yo,
                                          float& c, float& h) {
    yi = __builtin_amdgcn_fmed3f(yi, -24.53f, 24.53f);
    yf = __builtin_amdgcn_fmed3f(yf, -24.53f, 24.53f);
    yo = __builtin_amdgcn_fmed3f(yo, -24.53f, 24.53f);
    yg = __builtin_amdgcn_fmed3f(yg, -31.74f, 31.74f);
    const float ei = fexp2r(yi), ef = fexp2r(yf), eo = fexp2r(yo), eg = fexp2r(yg);
    const float di = 1.f + ei, df = 1.f + ef, dd = 1.f + eo, dg = 1.f + eg;
    const float a = di * df, b = dd * dg;
    const float R = __builtin_amdgcn_rcpf(a * b);
    const float si = df * b * R;
    const float sf = di * b * R;
    const float so = a * dg * R;
    const float tg = (eg - 1.f) * (a * dd) * R;
    const float cn = sf * c + si * tg;
    c = cn;
    const float tc = __builtin_amdgcn_fmed3f(cn, -11.f, 11.f);
    const float ec = fexp2r(tc * (2.f * L2E));
    const float th = (ec - 1.f) * __builtin_amdgcn_rcpf(ec + 1.f);
    h = so * th;
}

// Step barrier: LDS-only drain; global ops stay in flight.
#define STEP_BARRIER() do {                                   \
    asm volatile("s_waitcnt lgkmcnt(0)" ::: "memory");        \
    __builtin_amdgcn_s_barrier();                             \
    __builtin_amdgcn_sched_barrier(0);                        \
} while (0)

__device__ __forceinline__ bf16x8 pack8s(float4 a, float4 b, float s) {
    bf16x8 r;
    r[0] = (short)f2bs(a.x * s); r[1] = (short)f2bs(a.y * s);
    r[2] = (short)f2bs(a.z * s); r[3] = (short)f2bs(a.w * s);
    r[4] = (short)f2bs(b.x * s); r[5] = (short)f2bs(b.y * s);
    r[6] = (short)f2bs(b.z * s); r[7] = (short)f2bs(b.w * s);
    return r;
}

// ================= FUSED: LSTM1 (reverse) then LSTM2 (forward) + heads =================
// R14 exact build (best: 228.2 us). 4 waves, M=32, launch_bounds(256,2);
// exp2-folded weights + native v_exp_f32 in the cell.
__global__ __launch_bounds__(256, 2) void k_fused(
    const float* __restrict__ xmain, const float* __restrict__ aux,
    const float* __restrict__ Ws1, const float* __restrict__ bs1,
    const float* __restrict__ Ws2, const float* __restrict__ bs2,
    const float* __restrict__ Wih1, const float* __restrict__ Whh1,
    const float* __restrict__ bih1, const float* __restrict__ bhh1,
    const float* __restrict__ hx2, const float* __restrict__ cx2,
    const float* __restrict__ Wih2, const float* __restrict__ Whh2,
    const float* __restrict__ bih2, const float* __restrict__ bhh2,
    const float* __restrict__ Wlat, const float* __restrict__ blat,
    const float* __restrict__ Wout, const float* __restrict__ bout,
    const float* __restrict__ Wsfc, const float* __restrict__ bsfc,
    unsigned short* __restrict__ rnn1t, float* __restrict__ out)
{
    __shared__ unsigned short hB[2 * 4096];     // [buf][32][128] bf16, XOR-swizzled
    __shared__ unsigned short whead[16 * 64];   // head B-tile (phase B); rows 7..15 stay 0

    const int tid = threadIdx.x;
    {
        unsigned int* w32 = (unsigned int*)whead;
        w32[tid] = 0; w32[tid + 256] = 0;
    }
    const int hj = tid >> 6, lane = tid & 63;
    const int row16 = lane & 15, quad = lane >> 4;
    const int b0 = blockIdx.x * 32;
    const int swz = (row16 & 7) << 3;
    char* const hBb = (char*)hB;
    char* const whb = (char*)whead;

    // shared LDS byte offsets ([32][128] layout, both phases)
    const int j = hj * 16 + row16;
    const unsigned oA0 = (unsigned)(((row16 * 128 + 0 + quad * 8) ^ swz) * 2);
    const unsigned oA1 = (unsigned)(((row16 * 128 + 32 + quad * 8) ^ swz) * 2);
    const unsigned oA2 = (unsigned)(((row16 * 128 + 64 + quad * 8) ^ swz) * 2);
    const unsigned oA3 = (unsigned)(((row16 * 128 + 96 + quad * 8) ^ swz) * 2);
    unsigned oW[4];
    #pragma unroll
    for (int r = 0; r < 4; ++r) {
        const int m = quad * 4 + r;
        oW[r] = (unsigned)(((m * 128 + j) ^ ((m & 7) << 3)) * 2);
    }

    // ============================ PHASE A: LSTM1 ============================
    {
        {   // zero hB (cols 64..95 must be 0 for the a2 tail)
            unsigned int* p32 = (unsigned int*)hB;
            #pragma unroll
            for (int e = 0; e < 16; ++e) p32[tid + 256 * e] = 0;
        }
        // B fragments from GLOBAL, exp2-folded per gate (i,f,o: -L2E; g: +2*L2E)
        bf16x8 wf[4][3];
        float fb[4];
        #pragma unroll
        for (int i = 0; i < 4; ++i) {
            const float s = (i == 2) ? (2.f * L2E) : (-L2E);
            const int g = (hj + 4 * i) * 16 + row16;
            const float* wr = Whh1 + g * 64 + quad * 8;
            wf[i][0] = pack8s(*(const float4*)wr, *(const float4*)(wr + 4), s);
            wf[i][1] = pack8s(*(const float4*)(wr + 32), *(const float4*)(wr + 36), s);
            float4 z4 = {0.f, 0.f, 0.f, 0.f};
            float4 xw = z4;
            if (quad == 0) xw = *(const float4*)(Wih1 + g * 4);
            wf[i][2] = pack8s(xw, z4, s);
            fb[i] = (bih1[g] + bhh1[g]) * s;
        }
        __syncthreads();   // zero-init visible

        const unsigned oX = (unsigned)(((lane * 128 + 64) ^ ((lane & 7) << 3)) * 2);

        // init h0/c0 for both M-halves -> buf0 (surface MLP, unfolded)
        const float w10 = Ws1[j * 3], w11 = Ws1[j * 3 + 1], w12 = Ws1[j * 3 + 2], sb1v = bs1[j];
        const float w20 = Ws2[j * 3], w21 = Ws2[j * 3 + 1], w22 = Ws2[j * 3 + 2], sb2v = bs2[j];
        f32x4 cc[2];
        #pragma unroll
        for (int mh = 0; mh < 2; ++mh) {
            #pragma unroll
            for (int r = 0; r < 4; ++r) {
                const int m = mh * 16 + quad * 4 + r;
                const float a0v = aux[(b0 + m) * 3], a1v = aux[(b0 + m) * 3 + 1], a2v = aux[(b0 + m) * 3 + 2];
                float h0 = w10 * a0v + w11 * a1v + w12 * a2v + sb1v;
                float c0in = w20 * a0v + w21 * a1v + w22 * a2v + sb2v;
                c0in = __builtin_amdgcn_fmed3f(c0in, -11.f, 11.f);
                const float e0 = fexp2r(c0in * (2.f * L2E));
                cc[mh][r] = (e0 - 1.f) * __builtin_amdgcn_rcpf(e0 + 1.f);
                *(unsigned short*)(hBb + oW[r] + mh * 4096) = f2bs(h0);
            }
        }
        if (hj == 2 && lane < 32) {   // stage x_59 (rows 0..31) into buf0
            float4 xv = ((const float4*)xmain)[(size_t)(b0 + lane) * TT + 59];
            uint2 p2 = { cvtpk2(xv.x, xv.y), cvtpk2(xv.z, xv.w) };
            *(uint2*)(hBb + oX) = p2;
        }
        __syncthreads();

        // running global pointers
        const float4* px = (const float4*)xmain + (size_t)(b0 + lane) * TT + 58;
        unsigned short* pst = rnn1t + ((size_t)60 * BB + b0 + ((hj >> 1) << 4) + row16) * 64 + ((hj & 1) << 5) + quad * 8;

        unsigned pofs = 0;
        #pragma unroll 1
        for (int s = 0; s < TT; ++s) {
            char* hbP = hBb + pofs;
            char* hbN = hBb + (pofs ^ 8192);
            float4 xv;
            if (hj == 2 && lane < 32 && s < TT - 1) xv = *px;   // prefetch x_{t-1}
            bf16x8 a0[2], a1[2], a2[2];
            #pragma unroll
            for (int mh = 0; mh < 2; ++mh) {
                a0[mh] = *(const bf16x8*)(hbP + oA0 + mh * 4096);
                a1[mh] = *(const bf16x8*)(hbP + oA1 + mh * 4096);
                a2[mh] = *(const bf16x8*)(hbP + oA2 + mh * 4096);
            }
            if (s > 0) {   // store h_{t+1}: each wave one quarter (fire-and-forget)
                bf16x8 sv = (hj == 0) ? a0[0] : (hj == 1) ? a1[0] : (hj == 2) ? a0[1] : a1[1];
                *(bf16x8*)pst = sv;
            }
            pst -= (size_t)BB * 64;
            px -= 1;

            f32x4 ac[2][4];
            #pragma unroll
            for (int mh = 0; mh < 2; ++mh)
                #pragma unroll
                for (int i = 0; i < 4; ++i) { f32x4 v = {fb[i], fb[i], fb[i], fb[i]}; ac[mh][i] = v; }
            #pragma unroll
            for (int mh = 0; mh < 2; ++mh) {
                #pragma unroll
                for (int i = 0; i < 4; ++i) {
                    ac[mh][i] = __builtin_amdgcn_mfma_f32_16x16x32_bf16(a0[mh], wf[i][0], ac[mh][i], 0, 0, 0);
                    ac[mh][i] = __builtin_amdgcn_mfma_f32_16x16x32_bf16(a1[mh], wf[i][1], ac[mh][i], 0, 0, 0);
                    ac[mh][i] = __builtin_amdgcn_mfma_f32_16x16x32_bf16(a2[mh], wf[i][2], ac[mh][i], 0, 0, 0);
                }
            }
            #pragma unroll
            for (int mh = 0; mh < 2; ++mh) {
                float hr[4];
                #pragma unroll
                for (int r = 0; r < 4; ++r) {
                    float cr = cc[mh][r];
                    lstm_cell(ac[mh][0][r], ac[mh][1][r], ac[mh][2][r], ac[mh][3][r], cr, hr[r]);
                    cc[mh][r] = cr;
                }
                const unsigned u01 = cvtpk2(hr[0], hr[1]);
                const unsigned u23 = cvtpk2(hr[2], hr[3]);
                *(unsigned short*)(hbN + oW[0] + mh * 4096) = (unsigned short)u01;
                *(unsigned short*)(hbN + oW[1] + mh * 4096) = (unsigned short)(u01 >> 16);
                *(unsigned short*)(hbN + oW[2] + mh * 4096) = (unsigned short)u23;
                *(unsigned short*)(hbN + oW[3] + mh * 4096) = (unsigned short)(u23 >> 16);
            }
            if (hj == 2 && lane < 32 && s < TT - 1) {
                uint2 p2 = { cvtpk2(xv.x, xv.y), cvtpk2(xv.z, xv.w) };
                *(uint2*)(hbN + oX) = p2;
            }
            STEP_BARRIER();
            pofs ^= 8192;
        }
        // epilogue: store h (slot 0)
        {
            char* hbP = hBb + pofs;
            bf16x8 sv;
            if (hj == 0)      sv = *(const bf16x8*)(hbP + oA0);
            else if (hj == 1) sv = *(const bf16x8*)(hbP + oA1);
            else if (hj == 2) sv = *(const bf16x8*)(hbP + oA0 + 4096);
            else              sv = *(const bf16x8*)(hbP + oA1 + 4096);
            *(bf16x8*)&rnn1t[((size_t)(b0 + ((hj >> 1) << 4) + row16)) * 64 + ((hj & 1) << 5) + quad * 8] = sv;
        }
    }

    // ---- transition: vmcnt(0)-draining barrier -> own rnn1t writes readable ----
    __syncthreads();

    // ============================ PHASE B: LSTM2 + heads ============================
    {
        // B fragments from GLOBAL, exp2-folded
        bf16x8 wf[4][4];
        float fb[4];
        #pragma unroll
        for (int i = 0; i < 4; ++i) {
            const float s = (i == 2) ? (2.f * L2E) : (-L2E);
            const int g = (hj + 4 * i) * 16 + row16;
            const float* wh = Whh2 + g * 64 + quad * 8;
            const float* wi = Wih2 + g * 64 + quad * 8;
            wf[i][0] = pack8s(*(const float4*)wh, *(const float4*)(wh + 4), s);
            wf[i][1] = pack8s(*(const float4*)(wh + 32), *(const float4*)(wh + 36), s);
            wf[i][2] = pack8s(*(const float4*)wi, *(const float4*)(wi + 4), s);
            wf[i][3] = pack8s(*(const float4*)(wi + 32), *(const float4*)(wi + 36), s);
            fb[i] = (bih2[g] + bhh2[g]) * s;
        }
        float bcomb = 0.f;
        if (row16 < 4) {
            float ss = 0.f;
            for (int jj = 0; jj < 64; ++jj) ss += Wout[row16 * 64 + jj] * blat[jj];
            bcomb = ss + bout[row16];
        } else if (row16 < 7) {
            bcomb = bsfc[row16 - 4];
        }
        {   // fill whead: rows 0..3 = Wout@Wlat, rows 4..6 = Wsfc (unfolded; rows 7..15 = 0)
            const int o = tid >> 6, k = tid & 63;
            float ss = 0.f;
            for (int jj = 0; jj < 64; ++jj) ss += Wout[o * 64 + jj] * Wlat[jj * 64 + k];
            whead[(o * 64 + k) ^ ((o & 7) << 3)] = f2bs(ss);
            if (tid < 192) {
                const int o2 = o + 4;
                whead[(o2 * 64 + k) ^ ((o2 & 7) << 3)] = f2bs(Wsfc[o * 64 + k]);
            }
        }

        const unsigned oPV = (unsigned)(((row16 * 128 + 64 + ((hj & 1) << 5) + quad * 8) ^ swz) * 2);
        const unsigned oH0 = (unsigned)(((row16 * 64 + 0 + quad * 8) ^ swz) * 2);
        const unsigned oH1 = (unsigned)(((row16 * 64 + 32 + quad * 8) ^ swz) * 2);

        // init h2_0/c2_0 -> buf0 (both halves)
        f32x4 cc[2];
        #pragma unroll
        for (int mh = 0; mh < 2; ++mh) {
            #pragma unroll
            for (int r = 0; r < 4; ++r) {
                const int m = mh * 16 + quad * 4 + r;
                cc[mh][r] = cx2[(size_t)(b0 + m) * 64 + j];
                *(unsigned short*)(hBb + oW[r] + mh * 4096) = f2bs(hx2[(size_t)(b0 + m) * 64 + j]);
            }
        }
        // stage h1_0 -> buf0 cols 64..127 (hj0: cols 0..31, hj1: cols 32..63; both halves)
        if (hj < 2) {
            bf16x8 v0 = *(const bf16x8*)&rnn1t[((size_t)(b0 + row16)) * 64 + ((hj & 1) << 5) + quad * 8];
            bf16x8 v1 = *(const bf16x8*)&rnn1t[((size_t)(b0 + 16 + row16)) * 64 + ((hj & 1) << 5) + quad * 8];
            *(bf16x8*)(hBb + oPV) = v0;
            *(bf16x8*)(hBb + oPV + 4096) = v1;
        }
        __syncthreads();

        // head fragments (used by hj2/hj3)
        bf16x8 wh0 = *(const bf16x8*)(whb + oH0);
        bf16x8 wh1 = *(const bf16x8*)(whb + oH1);

        // running global pointers
        const unsigned short* ppv = rnn1t + ((size_t)BB + b0 + row16) * 64 + ((hj & 1) << 5) + quad * 8;
        float* po = out + ((size_t)(b0 + ((hj == 2) ? 16 : 0) + quad * 4) * TT) * 4 + row16;

        unsigned pofs = 0;
        #pragma unroll 1
        for (int t = 0; t < TT; ++t) {
            char* hbP = hBb + pofs;
            char* hbN = hBb + (pofs ^ 8192);
            bf16x8 pv0, pv1;
            if (hj < 2 && t < TT - 1) {   // prefetch h1_{t+1}, both halves
                pv0 = *(const bf16x8*)ppv;
                pv1 = *(const bf16x8*)(ppv + 16 * 64);
            }
            ppv += (size_t)BB * 64;

            bf16x8 a0[2], a1[2], a2[2], a3[2];
            #pragma unroll
            for (int mh = 0; mh < 2; ++mh) {
                a0[mh] = *(const bf16x8*)(hbP + oA0 + mh * 4096);
                a1[mh] = *(const bf16x8*)(hbP + oA1 + mh * 4096);
                a2[mh] = *(const bf16x8*)(hbP + oA2 + mh * 4096);
                a3[mh] = *(const bf16x8*)(hbP + oA3 + mh * 4096);
            }

            if (hj >= 2 && t > 0) {   // head(h2_t, pre-update): hj3=mh0, hj2=mh1
                const bf16x8 ha0 = (hj == 3) ? a0[0] : a0[1];
                const bf16x8 ha1 = (hj == 3) ? a1[0] : a1[1];
                f32x4 hacc = {bcomb, bcomb, bcomb, bcomb};
                hacc = __builtin_amdgcn_mfma_f32_16x16x32_bf16(ha0, wh0, hacc, 0, 0, 0);
                hacc = __builtin_amdgcn_mfma_f32_16x16x32_bf16(ha1, wh1, hacc, 0, 0, 0);
                if (row16 < 4) {
                    #pragma unroll
                    for (int r = 0; r < 4; ++r)
                        po[r * TT * 4] = hacc[r];
                }
                po += 4;
            }

            f32x4 ac[2][4];
            #pragma unroll
            for (int mh = 0; mh < 2; ++mh)
                #pragma unroll
                for (int i = 0; i < 4; ++i) { f32x4 v = {fb[i], fb[i], fb[i], fb[i]}; ac[mh][i] = v; }
            #pragma unroll
            for (int mh = 0; mh < 2; ++mh) {
                #pragma unroll
                for (int i = 0; i < 4; ++i) {
                    ac[mh][i] = __builtin_amdgcn_mfma_f32_16x16x32_bf16(a0[mh], wf[i][0], ac[mh][i], 0, 0, 0);
                    ac[mh][i] = __builtin_amdgcn_mfma_f32_16x16x32_bf16(a1[mh], wf[i][1], ac[mh][i], 0, 0, 0);
                    ac[mh][i] = __builtin_amdgcn_mfma_f32_16x16x32_bf16(a2[mh], wf[i][2], ac[mh][i], 0, 0, 0);
                    ac[mh][i] = __builtin_amdgcn_mfma_f32_16x16x32_bf16(a3[mh], wf[i][3], ac[mh][i], 0, 0, 0);
                }
            }
            #pragma unroll
            for (int mh = 0; mh < 2; ++mh) {
                float hr[4];
                #pragma unroll
                for (int r = 0; r < 4; ++r) {
                    float cr = cc[mh][r];
                    lstm_cell(ac[mh][0][r], ac[mh][1][r], ac[mh][2][r], ac[mh][3][r], cr, hr[r]);
                    cc[mh][r] = cr;
                }
                const unsigned u01 = cvtpk2(hr[0], hr[1]);
                const unsigned u23 = cvtpk2(hr[2], hr[3]);
                *(unsigned short*)(hbN + oW[0] + mh * 4096) = (unsigned short)u01;
                *(unsigned short*)(hbN + oW[1] + mh * 4096) = (unsigned short)(u01 >> 16);
                *(unsigned short*)(hbN + oW[2] + mh * 4096) = (unsigned short)u23;
                *(unsigned short*)(hbN + oW[3] + mh * 4096) = (unsigned short)(u23 >> 16);
            }
            if (hj < 2 && t < TT - 1) {
                *(bf16x8*)(hbN + oPV) = pv0;
                *(bf16x8*)(hbN + oPV + 4096) = pv1;
            }
            STEP_BARRIER();
            pofs ^= 8192;
        }
        // epilogue: head(h2_60) -> slot 59 + relu sfc (hj3 = mh0, hj2 = mh1)
        if (hj >= 2) {
            char* hbP = hBb + pofs;
            const int mho = (hj == 3) ? 0 : 4096;
            bf16x8 ea0 = *(const bf16x8*)(hbP + oA0 + mho);
            bf16x8 ea1 = *(const bf16x8*)(hbP + oA1 + mho);
            f32x4 hacc = {bcomb, bcomb, bcomb, bcomb};
            hacc = __builtin_amdgcn_mfma_f32_16x16x32_bf16(ea0, wh0, hacc, 0, 0, 0);
            hacc = __builtin_amdgcn_mfma_f32_16x16x32_bf16(ea1, wh1, hacc, 0, 0, 0);
            const int rb = b0 + ((hj == 2) ? 16 : 0) + quad * 4;
            if (row16 < 4) {
                #pragma unroll
                for (int r = 0; r < 4; ++r)
                    out[((size_t)(rb + r) * TT + 59) * 4 + row16] = hacc[r];
            } else if (row16 < 7) {
                float* osfc = out + (size_t)BB * TT * 4;
                #pragma unroll
                for (int r = 0; r < 4; ++r)
                    osfc[(size_t)(rb + r) * 3 + (row16 - 4)] = fmaxf(hacc[r], 0.f);
            }
        }
    }
}

extern "C" void kernel_launch(void* const* d_in, const int* in_sizes, int n_in,
                              void* d_out, int out_size, void* d_ws, size_t ws_size,
                              hipStream_t stream) {
    const float* xmain = (const float*)d_in[0];
    const float* aux   = (const float*)d_in[1];
    const float* hx2   = (const float*)d_in[2];
    const float* cx2   = (const float*)d_in[3];
    const float* Ws1   = (const float*)d_in[4];
    const float* bs1   = (const float*)d_in[5];
    const float* Ws2   = (const float*)d_in[6];
    const float* bs2   = (const float*)d_in[7];
    const float* Wih1  = (const float*)d_in[8];
    const float* Whh1  = (const float*)d_in[9];
    const float* bih1  = (const float*)d_in[10];
    const float* bhh1  = (const float*)d_in[11];
    const float* Wih2  = (const float*)d_in[12];
    const float* Whh2  = (const float*)d_in[13];
    const float* bih2  = (const float*)d_in[14];
    const float* bhh2  = (const float*)d_in[15];
    const float* Wlat  = (const float*)d_in[16];
    const float* blat  = (const float*)d_in[17];
    const float* Wout  = (const float*)d_in[18];
    const float* bout  = (const float*)d_in[19];
    const float* Wsfc  = (const float*)d_in[20];
    const float* bsfc  = (const float*)d_in[21];

    unsigned short* rnn1t = (unsigned short*)d_ws;   // [T][B][64] bf16 (private per-block slices)
    float* out = (float*)d_out;

    dim3 grid(BB / 32), block(256);
    k_fused<<<grid, block, 0, stream>>>(xmain, aux, Ws1, bs1, Ws2, bs2,
                                        Wih1, Whh1, bih1, bhh1,
                                        hx2, cx2, Wih2, Whh2, bih2, bhh2,
                                        Wlat, blat, Wout, bout, Wsfc, bsfc,
                                        rnn1t, out);
}